// Round 3
// baseline (884.179 us; speedup 1.0000x reference)
//
#include <hip/hip_runtime.h>

typedef _Float16 half_t;
typedef __attribute__((ext_vector_type(8))) _Float16 half8;
typedef __attribute__((ext_vector_type(4))) _Float16 half4v;
typedef __attribute__((ext_vector_type(4))) float f32x4;

#define MFMA16(a,b,c) __builtin_amdgcn_mfma_f32_16x16x32_f16((a),(b),(c),0,0,0)

__device__ __forceinline__ void gld_lds16(const half_t* g, half_t* l){
    __builtin_amdgcn_global_load_lds((__attribute__((address_space(1))) void*)(g),
                                     (__attribute__((address_space(3))) void*)(l), 16, 0, 0);
}

// ---------------- fp32 -> fp16 convert ----------------
__global__ __launch_bounds__(256) void cvt_k(const float* __restrict__ s, half_t* __restrict__ d, int n4){
    int i = blockIdx.x * 256 + threadIdx.x;
    if (i < n4){
        float4 v = ((const float4*)s)[i];
        half4v h = { (half_t)v.x, (half_t)v.y, (half_t)v.z, (half_t)v.w };
        ((half4v*)d)[i] = h;
    }
}

// 4 weight matrices in one launch (grid.y selects)
__global__ __launch_bounds__(256) void cvtw_k(const float* __restrict__ w0, const float* __restrict__ w1,
                                              const float* __restrict__ w2, const float* __restrict__ w3,
                                              half_t* __restrict__ dst){
    const float* srcs[4] = {w0, w1, w2, w3};
    const float* s = srcs[blockIdx.y];
    int i = blockIdx.x * 256 + threadIdx.x;
    float4 v = ((const float4*)s)[i];
    half4v h = { (half_t)v.x, (half_t)v.y, (half_t)v.z, (half_t)v.w };
    ((half4v*)(dst))[(size_t)blockIdx.y * 1048576 + i] = h;
}

// ---------------- NT GEMM: C[m,n] = sum_k A[m,k]*B[n,k] ----------------
// LDS tiles XOR-swizzled (chunk-of-8 halves, phys = logical ^ (row&7)) -> conflict-free frag reads.
// kind 0: QKV fused (grid.y = 48; which = bn>>4): Q,K row-major [m][2048]; V -> Vt [bh][d][s] via LDS transpose.
// kind 1: O-proj, fp32 out row-major [m][n].
__global__ __launch_bounds__(256) void gemm_nt(const half_t* __restrict__ A, const half_t* __restrict__ B,
                                               half_t* __restrict__ Qw, half_t* __restrict__ Kw,
                                               half_t* __restrict__ Vt, float* __restrict__ Co, int kind){
    const int tid  = threadIdx.x;
    const int lane = tid & 63;
    const int w    = lane >> 4;
    const int l15  = lane & 15;
    const int l7   = lane & 7;
    const int wav  = tid >> 6;
    const int wm   = (wav >> 1) * 64;
    const int wn   = (wav & 1) * 64;
    const int bm   = blockIdx.x;
    const int bn   = blockIdx.y;
    const int KD   = 2048;

    __shared__ __align__(16) half_t smem[16384];   // As 8192 | Bs 8192 (reused as 128x128 C-tile in V epilogue)
    half_t* As = smem;
    half_t* Bs = smem + 8192;

    f32x4 acc[4][4] = {};

    const half_t* Ab = A + (size_t)bm * 128 * KD;
    const half_t* Bb = B + (size_t)bn * 128 * KD;

    for (int k0 = 0; k0 < KD; k0 += 64){
#pragma unroll
        for (int i = 0; i < 4; i++){
            int c = tid + i*256;
            int r = c >> 3, p = c & 7;
            gld_lds16(Ab + (size_t)r*KD + k0 + ((p ^ (r&7)) << 3), As + c*8);
        }
#pragma unroll
        for (int i = 0; i < 4; i++){
            int c = tid + i*256;
            int r = c >> 3, p = c & 7;
            gld_lds16(Bb + (size_t)r*KD + k0 + ((p ^ (r&7)) << 3), Bs + c*8);
        }
        __syncthreads();
#pragma unroll
        for (int ks = 0; ks < 2; ks++){
            half8 af[4], bf[4];
#pragma unroll
            for (int mi = 0; mi < 4; mi++)
                af[mi] = *(const half8*)(As + (wm + mi*16 + l15)*64 + (((ks*4 + w) ^ l7) << 3));
#pragma unroll
            for (int ni = 0; ni < 4; ni++)
                bf[ni] = *(const half8*)(Bs + (wn + ni*16 + l15)*64 + (((ks*4 + w) ^ l7) << 3));
#pragma unroll
            for (int mi = 0; mi < 4; mi++)
#pragma unroll
                for (int ni = 0; ni < 4; ni++)
                    acc[mi][ni] = MFMA16(af[mi], bf[ni], acc[mi][ni]);
        }
        __syncthreads();
    }

    const int rbase = wm + w*4;
    const int cbase = wn + l15;

    if (kind == 0){
        const int which = bn >> 4;
        const int nb = (bn & 15) * 128;
        if (which < 2){
            // Q/K row-major [b*2048+s][2048]
            half_t* dst = which ? Kw : Qw;
#pragma unroll
            for (int mi = 0; mi < 4; mi++)
#pragma unroll
                for (int ni = 0; ni < 4; ni++)
#pragma unroll
                    for (int r = 0; r < 4; r++){
                        int m = bm*128 + rbase + mi*16 + r;
                        int n = nb + cbase + ni*16;
                        dst[(size_t)m*2048 + n] = (half_t)acc[mi][ni][r];
                    }
        } else {
            // V -> Vt [bh][d][s] via LDS transpose (reuse smem as CT[n][m], swizzled)
#pragma unroll
            for (int mi = 0; mi < 4; mi++)
#pragma unroll
                for (int ni = 0; ni < 4; ni++){
                    int n  = cbase + ni*16;           // local d
                    int m0 = wm + mi*16 + w*4;        // local s-chunk base
                    half4v h = {(half_t)acc[mi][ni][0], (half_t)acc[mi][ni][1],
                                (half_t)acc[mi][ni][2], (half_t)acc[mi][ni][3]};
                    *(half4v*)(smem + n*128 + (((m0>>3) ^ (n&7)) << 3) + (m0 & 7)) = h;
                }
            __syncthreads();
            const int bh = (bm >> 4)*16 + (bn & 15);
            const int s0 = (bm & 15) * 128;
#pragma unroll
            for (int it = 0; it < 32; it++){
                int d = it*4 + w;
                half8 rd = *(const half8*)(smem + d*128 + ((l15 ^ (d&7)) << 3));
                *(half8*)(Vt + ((size_t)bh*128 + d)*2048 + s0 + l15*8) = rd;
            }
        }
    } else {
#pragma unroll
        for (int mi = 0; mi < 4; mi++)
#pragma unroll
            for (int ni = 0; ni < 4; ni++)
#pragma unroll
                for (int r = 0; r < 4; r++){
                    int m = bm*128 + rbase + mi*16 + r;
                    int n = bn*128 + cbase + ni*16;
                    Co[(size_t)m*2048 + n] = acc[mi][ni][r];
                }
    }
}

// ---------------- RoPE in-place on row-major Q/K [b*2048+s][h*128+d] ----------------
__global__ __launch_bounds__(256) void rope_k(half_t* __restrict__ Qw, half_t* __restrict__ Kw,
                                              const float* __restrict__ cs, const float* __restrict__ sn){
    int t = blockIdx.x * 256 + threadIdx.x;   // 8.4M threads
    int d = t & 63;
    int h = (t >> 6) & 15;
    int s = (t >> 10) & 2047;
    int b = t >> 21;
    float c  = cs[s*64 + d];
    float si = sn[s*64 + d];
    size_t base = ((size_t)(b*2048 + s))*2048 + h*128 + d;
    float q1 = (float)Qw[base], q2 = (float)Qw[base+64];
    Qw[base]    = (half_t)(q1*c - q2*si);
    Qw[base+64] = (half_t)(q1*si + q2*c);
    float k1 = (float)Kw[base], k2 = (float)Kw[base+64];
    Kw[base]    = (half_t)(k1*c - k2*si);
    Kw[base+64] = (half_t)(k1*si + k2*c);
}

// ---------------- Flash attention, S^T formulation ----------------
// Q,K row-major [b*2048+s][h*128+d]; Vt [bh][128][s] -> AO [b*2048+s][h*128+d]
__global__ __launch_bounds__(256, 3) void attn_k(const half_t* __restrict__ Q, const half_t* __restrict__ K,
                                                 const half_t* __restrict__ Vt, half_t* __restrict__ AO){
    const int tid  = threadIdx.x;
    const int lane = tid & 63;
    const int w    = lane >> 4;
    const int l15  = lane & 15;
    const int l7   = lane & 7;
    const int wav  = tid >> 6;
    const int qt   = blockIdx.x;   // 16 q-tiles of 128
    const int bh   = blockIdx.y;   // 64
    const int b    = bh >> 4, h = bh & 15;

    __shared__ __align__(16) half_t smem[8192 + 8192 + 4*2560];
    half_t* Ks = smem;
    half_t* Vs = smem + 8192;
    half_t* Ps = smem + 16384 + wav*2560;
    half_t* Ob = smem + wav*4096;

    // Q fragments held across K loop
    const half_t* Qb = Q + ((size_t)(b*2048 + qt*128 + wav*32))*2048 + h*128;
    half8 aq[2][4];
#pragma unroll
    for (int qi = 0; qi < 2; qi++)
#pragma unroll
        for (int ks = 0; ks < 4; ks++)
            aq[qi][ks] = *(const half8*)(Qb + (size_t)(qi*16 + l15)*2048 + ks*32 + w*8);

    f32x4 oacc[8][2] = {};
    float m_[2] = {-1e30f, -1e30f};
    float l_[2] = {0.0f, 0.0f};

    const float SSC = 0.08838834764831845f * 1.4426950408889634f;  // 1/sqrt(128) * log2(e)

    for (int kt = 0; kt < 32; kt++){
        const half_t* Kb = K  + ((size_t)(b*2048 + kt*64))*2048 + h*128;
        const half_t* Vb = Vt + (size_t)bh*128*2048 + kt*64;
        __syncthreads();
#pragma unroll
        for (int i = 0; i < 4; i++){
            int c = tid + i*256;
            int key = c >> 4, pc = c & 15;
            gld_lds16(Kb + (size_t)key*2048 + ((pc ^ (key&7)) << 3), Ks + c*8);
        }
#pragma unroll
        for (int i = 0; i < 4; i++){
            int c = tid + i*256;
            int d = c >> 3, pc = c & 7;
            gld_lds16(Vb + (size_t)d*2048 + ((pc ^ (d&7)) << 3), Vs + c*8);
        }
        __syncthreads();

        // S^T = K @ Q^T : rows=key (4 tiles), cols=q (2 tiles)
        f32x4 sacc[4][2] = {};
#pragma unroll
        for (int ks = 0; ks < 4; ks++){
#pragma unroll
            for (int t = 0; t < 4; t++){
                half8 kf = *(const half8*)(Ks + (t*16 + l15)*128 + (((ks*4 + w) ^ l7) << 3));
                sacc[t][0] = MFMA16(kf, aq[0][ks], sacc[t][0]);
                sacc[t][1] = MFMA16(kf, aq[1][ks], sacc[t][1]);
            }
        }

        // online softmax per q-column (per-lane state, replicated across quads)
#pragma unroll
        for (int qi = 0; qi < 2; qi++){
            float mx = sacc[0][qi][0];
#pragma unroll
            for (int t = 0; t < 4; t++)
#pragma unroll
                for (int r = 0; r < 4; r++) mx = fmaxf(mx, sacc[t][qi][r]);
            mx = fmaxf(mx, __shfl_xor(mx, 16));
            mx = fmaxf(mx, __shfl_xor(mx, 32));
            float mn = fmaxf(m_[qi], mx*SSC);
            float alpha = exp2f(m_[qi] - mn);
            m_[qi] = mn;
            float sum = 0.0f;
#pragma unroll
            for (int t = 0; t < 4; t++){
                float p0 = exp2f(sacc[t][qi][0]*SSC - mn);
                float p1 = exp2f(sacc[t][qi][1]*SSC - mn);
                float p2 = exp2f(sacc[t][qi][2]*SSC - mn);
                float p3 = exp2f(sacc[t][qi][3]*SSC - mn);
                sum += (p0 + p1) + (p2 + p3);
                half4v hv = {(half_t)p0, (half_t)p1, (half_t)p2, (half_t)p3};
                *(half4v*)(Ps + (qi*16 + l15)*80 + t*16 + w*4) = hv;
            }
            sum += __shfl_xor(sum, 16);
            sum += __shfl_xor(sum, 32);
            l_[qi] = l_[qi]*alpha + sum;
#pragma unroll
            for (int t = 0; t < 8; t++)
#pragma unroll
                for (int r = 0; r < 4; r++) oacc[t][qi][r] *= alpha;
        }

        // O^T += V^T @ P^T
#pragma unroll
        for (int c2 = 0; c2 < 2; c2++){
            half8 pf0 = *(const half8*)(Ps + l15*80        + c2*32 + w*8);
            half8 pf1 = *(const half8*)(Ps + (16 + l15)*80 + c2*32 + w*8);
#pragma unroll
            for (int t = 0; t < 8; t++){
                half8 vf = *(const half8*)(Vs + (t*16 + l15)*64 + (((c2*4 + w) ^ l7) << 3));
                oacc[t][0] = MFMA16(vf, pf0, oacc[t][0]);
                oacc[t][1] = MFMA16(vf, pf1, oacc[t][1]);
            }
        }
    }

    // epilogue: transpose O^T -> O through LDS, coalesced global stores
    float inv[2] = {1.0f / l_[0], 1.0f / l_[1]};
    __syncthreads();
#pragma unroll
    for (int t = 0; t < 8; t++)
#pragma unroll
        for (int qi = 0; qi < 2; qi++){
            int q  = qi*16 + l15;
            int c8 = t*2 + (w>>1);
            int pc = c8 ^ l7;
            half4v hv = {(half_t)(oacc[t][qi][0]*inv[qi]), (half_t)(oacc[t][qi][1]*inv[qi]),
                         (half_t)(oacc[t][qi][2]*inv[qi]), (half_t)(oacc[t][qi][3]*inv[qi])};
            *(half4v*)(Ob + q*128 + pc*8 + (w&1)*4) = hv;
        }
#pragma unroll
    for (int it = 0; it < 8; it++){
        int q  = it*4 + w;
        half8 rd = *(const half8*)(Ob + q*128 + ((l15 ^ (q&7)) << 3));
        int s = qt*128 + wav*32 + q;
        *(half8*)(AO + ((size_t)(b*2048 + s))*2048 + h*128 + l15*8) = rd;
    }
}

extern "C" void kernel_launch(void* const* d_in, const int* in_sizes, int n_in,
                              void* d_out, int out_size, void* d_ws, size_t ws_size,
                              hipStream_t stream){
    const float* x  = (const float*)d_in[0];
    const float* cs = (const float*)d_in[1];
    const float* sn = (const float*)d_in[2];
    const float* Wq = (const float*)d_in[3];
    const float* Wk = (const float*)d_in[4];
    const float* Wv = (const float*)d_in[5];
    const float* Wo = (const float*)d_in[6];

    half_t* ws = (half_t*)d_ws;
    half_t* xh = ws;
    half_t* w4 = ws + (size_t)16777216;
    half_t* qw = ws + (size_t)33554432;
    half_t* kw = ws + (size_t)50331648;
    half_t* vt = ws + (size_t)67108864;
    half_t* ao = ws + (size_t)83886080;

    cvt_k<<<16384, 256, 0, stream>>>(x, xh, 4194304);
    cvtw_k<<<dim3(4096, 4), 256, 0, stream>>>(Wq, Wk, Wv, Wo, w4);

    gemm_nt<<<dim3(64, 48), 256, 0, stream>>>(xh, w4, qw, kw, vt, nullptr, 0);
    rope_k<<<32768, 256, 0, stream>>>(qw, kw, cs, sn);
    attn_k<<<dim3(16, 64), 256, 0, stream>>>(qw, kw, vt, ao);
    gemm_nt<<<dim3(64, 16), 256, 0, stream>>>(ao, w4 + 12582912, nullptr, nullptr, nullptr,
                                              (float*)d_out, 1);
}

// Round 4
// 788.870 us; speedup vs baseline: 1.1208x; 1.1208x over previous
//
#include <hip/hip_runtime.h>

typedef _Float16 half_t;
typedef __attribute__((ext_vector_type(8))) _Float16 half8;
typedef __attribute__((ext_vector_type(4))) _Float16 half4v;
typedef __attribute__((ext_vector_type(4))) float f32x4;

#define MFMA16(a,b,c) __builtin_amdgcn_mfma_f32_16x16x32_f16((a),(b),(c),0,0,0)

__device__ __forceinline__ void gld_lds16(const half_t* g, half_t* l){
    __builtin_amdgcn_global_load_lds((__attribute__((address_space(1))) void*)(g),
                                     (__attribute__((address_space(3))) void*)(l), 16, 0, 0);
}

// ---------------- fp32 -> fp16 convert ----------------
__global__ __launch_bounds__(256) void cvt_k(const float* __restrict__ s, half_t* __restrict__ d, int n4){
    int i = blockIdx.x * 256 + threadIdx.x;
    if (i < n4){
        float4 v = ((const float4*)s)[i];
        half4v h = { (half_t)v.x, (half_t)v.y, (half_t)v.z, (half_t)v.w };
        ((half4v*)d)[i] = h;
    }
}

__global__ __launch_bounds__(256) void cvtw_k(const float* __restrict__ w0, const float* __restrict__ w1,
                                              const float* __restrict__ w2, const float* __restrict__ w3,
                                              half_t* __restrict__ dst){
    const float* srcs[4] = {w0, w1, w2, w3};
    const float* s = srcs[blockIdx.y];
    int i = blockIdx.x * 256 + threadIdx.x;
    float4 v = ((const float4*)s)[i];
    half4v h = { (half_t)v.x, (half_t)v.y, (half_t)v.z, (half_t)v.w };
    ((half4v*)(dst))[(size_t)blockIdx.y * 1048576 + i] = h;
}

// ---------------- NT GEMM: C[m,n] = sum_k A[m,k]*B[n,k] ----------------
// LDS tiles XOR-swizzled (chunk-of-8 halves, phys = logical ^ (row&7)) -> conflict-free frag reads.
// kind 0: QKV fused (grid.y=48; which=bn>>4): Q,K -> [b,h,s,d]; V -> Vt [b,h,d,s].
// kind 1: O-proj, fp32 out row-major [m][n].
__global__ __launch_bounds__(256) void gemm_nt(const half_t* __restrict__ A, const half_t* __restrict__ B,
                                               half_t* __restrict__ Qw, half_t* __restrict__ Kw,
                                               half_t* __restrict__ Vt, float* __restrict__ Co, int kind){
    const int tid  = threadIdx.x;
    const int lane = tid & 63;
    const int w    = lane >> 4;
    const int l15  = lane & 15;
    const int l7   = lane & 7;
    const int wav  = tid >> 6;
    const int wm   = (wav >> 1) * 64;
    const int wn   = (wav & 1) * 64;
    const int bm   = blockIdx.x;
    const int bn   = blockIdx.y;
    const int KD   = 2048;

    __shared__ __align__(16) half_t smem[16384];
    half_t* As = smem;
    half_t* Bs = smem + 8192;

    f32x4 acc[4][4] = {};

    const half_t* Ab = A + (size_t)bm * 128 * KD;
    const half_t* Bb = B + (size_t)bn * 128 * KD;

    for (int k0 = 0; k0 < KD; k0 += 64){
#pragma unroll
        for (int i = 0; i < 4; i++){
            int c = tid + i*256;
            int r = c >> 3, p = c & 7;
            gld_lds16(Ab + (size_t)r*KD + k0 + ((p ^ (r&7)) << 3), As + c*8);
        }
#pragma unroll
        for (int i = 0; i < 4; i++){
            int c = tid + i*256;
            int r = c >> 3, p = c & 7;
            gld_lds16(Bb + (size_t)r*KD + k0 + ((p ^ (r&7)) << 3), Bs + c*8);
        }
        __syncthreads();
#pragma unroll
        for (int ks = 0; ks < 2; ks++){
            half8 af[4], bf[4];
#pragma unroll
            for (int mi = 0; mi < 4; mi++)
                af[mi] = *(const half8*)(As + (wm + mi*16 + l15)*64 + (((ks*4 + w) ^ l7) << 3));
#pragma unroll
            for (int ni = 0; ni < 4; ni++)
                bf[ni] = *(const half8*)(Bs + (wn + ni*16 + l15)*64 + (((ks*4 + w) ^ l7) << 3));
#pragma unroll
            for (int mi = 0; mi < 4; mi++)
#pragma unroll
                for (int ni = 0; ni < 4; ni++)
                    acc[mi][ni] = MFMA16(af[mi], bf[ni], acc[mi][ni]);
        }
        __syncthreads();
    }

    const int rbase = wm + w*4;
    const int cbase = wn + l15;

    if (kind == 0){
        const int which = bn >> 4;
        const int nb = (bn & 15) * 128;
        if (which < 2){
            half_t* dst = which ? Kw : Qw;
#pragma unroll
            for (int mi = 0; mi < 4; mi++)
#pragma unroll
                for (int ni = 0; ni < 4; ni++)
#pragma unroll
                    for (int r = 0; r < 4; r++){
                        int m = bm*128 + rbase + mi*16 + r;
                        int n = nb + cbase + ni*16;
                        dst[(((size_t)(m>>11)*16 + (n>>7))*2048 + (m&2047))*128 + (n&127)] = (half_t)acc[mi][ni][r];
                    }
        } else {
#pragma unroll
            for (int mi = 0; mi < 4; mi++)
#pragma unroll
                for (int ni = 0; ni < 4; ni++){
                    int m0 = bm*128 + rbase + mi*16;
                    int n  = nb + cbase + ni*16;
                    half4v h = {(half_t)acc[mi][ni][0], (half_t)acc[mi][ni][1],
                                (half_t)acc[mi][ni][2], (half_t)acc[mi][ni][3]};
                    *(half4v*)(Vt + (((size_t)(m0>>11)*16 + (n>>7))*128 + (n&127))*2048 + (m0&2047)) = h;
                }
        }
    } else {
#pragma unroll
        for (int mi = 0; mi < 4; mi++)
#pragma unroll
            for (int ni = 0; ni < 4; ni++)
#pragma unroll
                for (int r = 0; r < 4; r++){
                    int m = bm*128 + rbase + mi*16 + r;
                    int n = bn*128 + cbase + ni*16;
                    Co[(size_t)m*2048 + n] = acc[mi][ni][r];
                }
    }
}

// ---------------- RoPE in-place on Q/K [b*16+h][s][128] ----------------
__global__ __launch_bounds__(256) void rope_k(half_t* __restrict__ Qw, half_t* __restrict__ Kw,
                                              const float* __restrict__ cs, const float* __restrict__ sn){
    int t  = blockIdx.x * 256 + threadIdx.x;
    int d  = t & 63;
    int s  = (t >> 6) & 2047;
    int bh = t >> 17;
    float c  = cs[s*64 + d];
    float si = sn[s*64 + d];
    size_t base = ((size_t)bh*2048 + s)*128 + d;
    float q1 = (float)Qw[base], q2 = (float)Qw[base+64];
    Qw[base]    = (half_t)(q1*c - q2*si);
    Qw[base+64] = (half_t)(q1*si + q2*c);
    float k1 = (float)Kw[base], k2 = (float)Kw[base+64];
    Kw[base]    = (half_t)(k1*c - k2*si);
    Kw[base+64] = (half_t)(k1*si + k2*c);
}

// ---------------- Flash attention, S^T formulation ----------------
// Q[bh][s][128], K[bh][s][128], Vt[bh][128][s] -> AO [b*2048+s][h*128+d]
__global__ __launch_bounds__(256, 3) void attn_k(const half_t* __restrict__ Q, const half_t* __restrict__ K,
                                                 const half_t* __restrict__ Vt, half_t* __restrict__ AO){
    const int tid  = threadIdx.x;
    const int lane = tid & 63;
    const int w    = lane >> 4;
    const int l15  = lane & 15;
    const int l7   = lane & 7;
    const int wav  = tid >> 6;
    const int qt   = blockIdx.x;   // 16 q-tiles of 128
    const int bh   = blockIdx.y;   // 64

    // Ks 16KB | Vs 16KB | Ps 4 x (32x72) 18KB. Ob overlays Ks+Vs after K loop.
    __shared__ __align__(16) half_t smem[8192 + 8192 + 4*2304];
    half_t* Ks = smem;
    half_t* Vs = smem + 8192;
    half_t* Ps = smem + 16384 + wav*2304;
    half_t* Ob = smem + wav*4096;

    const half_t* Qb = Q + ((size_t)bh*2048 + qt*128 + wav*32)*128;
    half8 aq[2][4];
#pragma unroll
    for (int qi = 0; qi < 2; qi++)
#pragma unroll
        for (int ks = 0; ks < 4; ks++)
            aq[qi][ks] = *(const half8*)(Qb + (qi*16 + l15)*128 + ks*32 + w*8);

    f32x4 oacc[8][2] = {};
    float m_[2] = {-1e30f, -1e30f};
    float l_[2] = {0.0f, 0.0f};

    const float SSC = 0.08838834764831845f * 1.4426950408889634f;  // 1/sqrt(128) * log2(e)

    for (int kt = 0; kt < 32; kt++){
        const half_t* Kb = K  + ((size_t)bh*2048 + kt*64)*128;
        const half_t* Vb = Vt + (size_t)bh*128*2048 + kt*64;
        __syncthreads();
#pragma unroll
        for (int i = 0; i < 4; i++){
            int c = tid + i*256;
            int key = c >> 4, pc = c & 15;
            gld_lds16(Kb + key*128 + ((pc ^ (key&7)) << 3), Ks + c*8);
        }
#pragma unroll
        for (int i = 0; i < 4; i++){
            int c = tid + i*256;
            int d = c >> 3, pc = c & 7;
            gld_lds16(Vb + (size_t)d*2048 + ((pc ^ (d&7)) << 3), Vs + c*8);
        }
        __syncthreads();

        // S^T = K @ Q^T : rows=key (4 tiles), cols=q (2 tiles)
        f32x4 sacc[4][2] = {};
#pragma unroll
        for (int ks = 0; ks < 4; ks++){
#pragma unroll
            for (int t = 0; t < 4; t++){
                half8 kf = *(const half8*)(Ks + (t*16 + l15)*128 + (((ks*4 + w) ^ l7) << 3));
                sacc[t][0] = MFMA16(kf, aq[0][ks], sacc[t][0]);
                sacc[t][1] = MFMA16(kf, aq[1][ks], sacc[t][1]);
            }
        }

        // online softmax per q-column (per-lane state, replicated across quads)
#pragma unroll
        for (int qi = 0; qi < 2; qi++){
            float mx = sacc[0][qi][0];
#pragma unroll
            for (int t = 0; t < 4; t++)
#pragma unroll
                for (int r = 0; r < 4; r++) mx = fmaxf(mx, sacc[t][qi][r]);
            mx = fmaxf(mx, __shfl_xor(mx, 16));
            mx = fmaxf(mx, __shfl_xor(mx, 32));
            float mn = fmaxf(m_[qi], mx*SSC);
            float alpha = exp2f(m_[qi] - mn);
            m_[qi] = mn;
            float sum = 0.0f;
#pragma unroll
            for (int t = 0; t < 4; t++){
                float p0 = exp2f(sacc[t][qi][0]*SSC - mn);
                float p1 = exp2f(sacc[t][qi][1]*SSC - mn);
                float p2 = exp2f(sacc[t][qi][2]*SSC - mn);
                float p3 = exp2f(sacc[t][qi][3]*SSC - mn);
                sum += (p0 + p1) + (p2 + p3);
                half4v hv = {(half_t)p0, (half_t)p1, (half_t)p2, (half_t)p3};
                *(half4v*)(Ps + (qi*16 + l15)*72 + t*16 + w*4) = hv;
            }
            sum += __shfl_xor(sum, 16);
            sum += __shfl_xor(sum, 32);
            l_[qi] = l_[qi]*alpha + sum;
#pragma unroll
            for (int t = 0; t < 8; t++)
#pragma unroll
                for (int r = 0; r < 4; r++) oacc[t][qi][r] *= alpha;
        }

        // O^T += V^T @ P^T
#pragma unroll
        for (int c2 = 0; c2 < 2; c2++){
            half8 pf0 = *(const half8*)(Ps + l15*72        + c2*32 + w*8);
            half8 pf1 = *(const half8*)(Ps + (16 + l15)*72 + c2*32 + w*8);
#pragma unroll
            for (int t = 0; t < 8; t++){
                half8 vf = *(const half8*)(Vs + (t*16 + l15)*64 + (((c2*4 + w) ^ l7) << 3));
                oacc[t][0] = MFMA16(vf, pf0, oacc[t][0]);
                oacc[t][1] = MFMA16(vf, pf1, oacc[t][1]);
            }
        }
    }

    // epilogue: transpose O^T -> O through LDS, coalesced global stores
    float inv[2] = {1.0f / l_[0], 1.0f / l_[1]};
    __syncthreads();
#pragma unroll
    for (int t = 0; t < 8; t++)
#pragma unroll
        for (int qi = 0; qi < 2; qi++){
            int q  = qi*16 + l15;
            int c8 = t*2 + (w>>1);
            int pc = c8 ^ l7;
            half4v hv = {(half_t)(oacc[t][qi][0]*inv[qi]), (half_t)(oacc[t][qi][1]*inv[qi]),
                         (half_t)(oacc[t][qi][2]*inv[qi]), (half_t)(oacc[t][qi][3]*inv[qi])};
            *(half4v*)(Ob + q*128 + pc*8 + (w&1)*4) = hv;
        }
    const int b = bh >> 4, h = bh & 15;
#pragma unroll
    for (int it = 0; it < 8; it++){
        int q  = it*4 + w;
        half8 rd = *(const half8*)(Ob + q*128 + ((l15 ^ (q&7)) << 3));
        int s = qt*128 + wav*32 + q;
        *(half8*)(AO + ((size_t)(b*2048 + s))*2048 + h*128 + l15*8) = rd;
    }
}

extern "C" void kernel_launch(void* const* d_in, const int* in_sizes, int n_in,
                              void* d_out, int out_size, void* d_ws, size_t ws_size,
                              hipStream_t stream){
    const float* x  = (const float*)d_in[0];
    const float* cs = (const float*)d_in[1];
    const float* sn = (const float*)d_in[2];
    const float* Wq = (const float*)d_in[3];
    const float* Wk = (const float*)d_in[4];
    const float* Wv = (const float*)d_in[5];
    const float* Wo = (const float*)d_in[6];

    half_t* ws = (half_t*)d_ws;
    half_t* xh = ws;
    half_t* w4 = ws + (size_t)16777216;
    half_t* qw = ws + (size_t)33554432;
    half_t* kw = ws + (size_t)50331648;
    half_t* vt = ws + (size_t)67108864;
    half_t* ao = ws + (size_t)83886080;

    cvt_k<<<16384, 256, 0, stream>>>(x, xh, 4194304);
    cvtw_k<<<dim3(4096, 4), 256, 0, stream>>>(Wq, Wk, Wv, Wo, w4);

    gemm_nt<<<dim3(64, 48), 256, 0, stream>>>(xh, w4, qw, kw, vt, nullptr, 0);
    rope_k<<<32768, 256, 0, stream>>>(qw, kw, cs, sn);
    attn_k<<<dim3(16, 64), 256, 0, stream>>>(qw, kw, vt, ao);
    gemm_nt<<<dim3(64, 16), 256, 0, stream>>>(ao, w4 + 12582912, nullptr, nullptr, nullptr,
                                              (float*)d_out, 1);
}